// Round 4
// baseline (9388.670 us; speedup 1.0000x reference)
//
#include <hip/hip_runtime.h>

#define NB   32
#define C    64
#define T    512
#define V    25
#define KP   3
#define CO   64
#define H    4
#define DKD  16
#define DVD  16
#define BN_EPS 1e-5f
#define LN_EPS 1e-6f

// ---------------------------------------------------------------------------
// scn union-LDS layout (float offsets into s_u[7396] = 29584 B):
//   phase P1 : PW  [0    .. 4992)   pw[192][26]
//   phase P2 : QN  [4992 .. 6642)   qn[25][66]     (pw still live, disjoint)
//   phase P3 : Q   [0    .. 1625)   q[25][65]      (pw dead)
//              K   [1632 .. 3257)   k[25][65]
//              VV  [3264 .. 4889)   vv[25][65]
//   phase P4 : ATT [4896 .. 7396)   att[4][25][25] (qn dead)
//   phase P5 : XH  [0    .. 1650)   xh[25][66]     (q,k dead)
// Total LDS = s_inp 6656 + mu/rstd 200 + 29584 = ~36.4 KB -> 4 blocks/CU.
// ---------------------------------------------------------------------------
#define OFF_PW  0
#define OFF_QN  4992
#define OFF_Q   0
#define OFF_K   1632
#define OFF_V   3264
#define OFF_ATT 4896
#define OFF_XH  0

__global__ __launch_bounds__(256, 4) void scn_kernel(
    const float* __restrict__ x, const float* __restrict__ A,
    const float* __restrict__ bn1_g, const float* __restrict__ bn1_b,
    const float* __restrict__ bn1_m, const float* __restrict__ bn1_v,
    const float* __restrict__ pconv_w, const float* __restrict__ pconv_b,
    const float* __restrict__ wq, const float* __restrict__ wk,
    const float* __restrict__ wv, const float* __restrict__ fc_w,
    const float* __restrict__ ln_g, const float* __restrict__ ln_b,
    const float* __restrict__ gate_w,
    const float* __restrict__ bn2_g, const float* __restrict__ bn2_b,
    const float* __restrict__ bn2_m, const float* __restrict__ bn2_v,
    float* __restrict__ f_out)
{
    const int nt  = blockIdx.x;
    const int n   = nt / T;
    const int t   = nt - n * T;
    const int tid = threadIdx.x;

    __shared__ float s_inp[C][26];          // bn1(x)[c][v], stride 26
    __shared__ float s_mu[V], s_rstd[V];
    __shared__ float s_u[7396];             // union region

    float r_agg[7];                         // agg[c][v] for i = tid + j*256

    // ---- P0: load x slice with bn1 applied ----
    for (int i = tid; i < C * V; i += 256) {
        int c = i / V, v = i - c * V;
        float s1 = bn1_g[c] * rsqrtf(bn1_v[c] + BN_EPS);
        float b1 = bn1_b[c] - bn1_m[c] * s1;
        s_inp[c][v] = x[((n * C + c) * T + t) * V + v] * s1 + b1;
    }
    __syncthreads();

    // ---- P1: pointwise partconv -> PW ; LN stats ----
    for (int i = tid; i < KP * CO * V; i += 256) {
        int o = i / V, v = i - o * V;
        float acc = pconv_b[o];
        const float* wrow = pconv_w + o * C;
        #pragma unroll 8
        for (int ci = 0; ci < C; ++ci) acc += wrow[ci] * s_inp[ci][v];
        s_u[OFF_PW + o * 26 + v] = acc;
    }
    if (tid < V) {
        float mu = 0.f;
        for (int c = 0; c < C; ++c) mu += s_inp[c][tid];
        mu *= (1.f / C);
        float var = 0.f;
        for (int c = 0; c < C; ++c) { float d = s_inp[c][tid] - mu; var += d * d; }
        var *= (1.f / C);
        s_mu[tid]   = mu;
        s_rstd[tid] = rsqrtf(var + LN_EPS);
    }
    __syncthreads();

    // ---- P2: qn = LN(fa) -> QN ; graph aggregation -> r_agg ----
    for (int i = tid; i < V * C; i += 256) {
        int v = i / C, c = i - v * C;
        s_u[OFF_QN + v * 66 + c] =
            (s_inp[c][v] - s_mu[v]) * s_rstd[v] * ln_g[c] + ln_b[c];
    }
    #pragma unroll
    for (int j = 0; j < 7; ++j) {
        int i = tid + j * 256;
        if (i < CO * V) {
            int c = i / V, w = i - c * V;
            float acc = 0.f;
            for (int k = 0; k < KP; ++k) {
                const float* pwr = &s_u[OFF_PW + (k * CO + c) * 26];
                const float* Ak  = A + k * V * V;
                #pragma unroll
                for (int v = 0; v < V; ++v) acc += pwr[v] * Ak[v * V + w];
            }
            r_agg[j] = acc;
        }
    }
    __syncthreads();

    // ---- P3: projections q = qn@wq, k = fa@wk, vv = fa@wv ----
    for (int i = tid; i < 3 * V * C; i += 256) {
        int which = i / (V * C);
        int rem   = i - which * (V * C);
        int v = rem / C, j = rem - v * C;
        float acc = 0.f;
        if (which == 0) {
            #pragma unroll 8
            for (int c = 0; c < C; ++c) acc += s_u[OFF_QN + v * 66 + c] * wq[c * C + j];
            s_u[OFF_Q + v * 65 + j] = acc;
        } else if (which == 1) {
            #pragma unroll 8
            for (int c = 0; c < C; ++c) acc += s_inp[c][v] * wk[c * C + j];
            s_u[OFF_K + v * 65 + j] = acc;
        } else {
            #pragma unroll 8
            for (int c = 0; c < C; ++c) acc += s_inp[c][v] * wv[c * C + j];
            s_u[OFF_V + v * 65 + j] = acc;
        }
    }
    __syncthreads();

    // ---- P4: attention scores + softmax -> ATT ----
    if (tid < H * V) {
        int h = tid / V, qv = tid - h * V;
        float qrow[DKD];
        #pragma unroll
        for (int d = 0; d < DKD; ++d) qrow[d] = s_u[OFF_Q + qv * 65 + h * DKD + d];
        float row[V];
        float mx = -1e30f;
        #pragma unroll
        for (int kv = 0; kv < V; ++kv) {
            float s = 0.f;
            #pragma unroll
            for (int d = 0; d < DKD; ++d)
                s += qrow[d] * s_u[OFF_K + kv * 65 + h * DKD + d];
            s *= 0.25f;                      // 1/sqrt(DK)
            row[kv] = s;
            mx = fmaxf(mx, s);
        }
        float sum = 0.f;
        #pragma unroll
        for (int kv = 0; kv < V; ++kv) { float e = __expf(row[kv] - mx); row[kv] = e; sum += e; }
        float inv = 1.f / sum;
        #pragma unroll
        for (int kv = 0; kv < V; ++kv)
            s_u[OFF_ATT + (h * V + qv) * V + kv] = row[kv] * inv;
    }
    __syncthreads();

    // ---- P5: xh = att @ vv -> XH ----
    for (int i = tid; i < V * C; i += 256) {
        int qv = i / C, j = i - qv * C;
        int h = j / DVD;
        float acc = 0.f;
        #pragma unroll
        for (int kv = 0; kv < V; ++kv)
            acc += s_u[OFF_ATT + (h * V + qv) * V + kv] * s_u[OFF_V + kv * 65 + j];
        s_u[OFF_XH + qv * 66 + j] = acc;
    }
    __syncthreads();

    // ---- P6: fc + residual ; gated fuse with r_agg ; bn2 ; relu ; store ----
    const float gate = gate_w[0];
    #pragma unroll
    for (int j = 0; j < 7; ++j) {
        int i = tid + j * 256;
        if (i < C * V) {
            int c = i / V, v = i - c * V;
            float acc = 0.f;
            #pragma unroll 8
            for (int d = 0; d < H * DVD; ++d)
                acc += s_u[OFF_XH + v * 66 + d] * fc_w[d * CO + c];
            float fa_out = acc + s_inp[c][v];              // residual (fa)
            float fv = (fa_out * gate + r_agg[j]) * 0.5f;
            float s2 = bn2_g[c] * rsqrtf(bn2_v[c] + BN_EPS);
            float b2 = bn2_b[c] - bn2_m[c] * s2;
            fv = fv * s2 + b2;
            f_out[((n * C + c) * T + t) * V + v] = fmaxf(fv, 0.f);
        }
    }
}

// ---------------------------------------------------------------------------
// Kernel 2: temporal conv (9,1) pad 4 + bias + bn3 + residual relu
// TB=4 time-steps per block; channel-split (2 passes of 32 ci) keeps LDS at
// 39.9 KB -> 4 blocks/CU. Each thread owns (co,v) pairs, reuses weights over
// the 4 time-steps in registers.
// ---------------------------------------------------------------------------
#define TBT 4
#define CIH 32

__global__ __launch_bounds__(256, 4) void tcn_kernel(
    const float* __restrict__ f, const float* __restrict__ x,
    const float* __restrict__ tconv_w, const float* __restrict__ tconv_b,
    const float* __restrict__ bn3_g, const float* __restrict__ bn3_b,
    const float* __restrict__ bn3_m, const float* __restrict__ bn3_v,
    float* __restrict__ out)
{
    const int bid  = blockIdx.x;
    const int n    = bid / (T / TBT);
    const int t0   = (bid - n * (T / TBT)) * TBT;
    const int tid  = threadIdx.x;

    __shared__ float s_f[CIH][TBT + 8][26];   // 39936 B

    float acc[7][TBT];
    #pragma unroll
    for (int j = 0; j < 7; ++j) {
        int p = tid + j * 256;
        if (p < CO * V) {
            float b = tconv_b[p / V];
            #pragma unroll
            for (int tb = 0; tb < TBT; ++tb) acc[j][tb] = b;
        }
    }

    for (int phase = 0; phase < 2; ++phase) {
        const int cb = phase * CIH;
        // stage f window [cb..cb+32) x [t0-4 .. t0+TBT+4) x V
        for (int i = tid; i < CIH * (TBT + 8) * V; i += 256) {
            int ci  = i / ((TBT + 8) * V);
            int rem = i - ci * ((TBT + 8) * V);
            int sl  = rem / V, v = rem - sl * V;
            int tt  = t0 + sl - 4;
            float val = 0.f;
            if (tt >= 0 && tt < T)
                val = f[((n * C + cb + ci) * T + tt) * V + v];
            s_f[ci][sl][v] = val;
        }
        __syncthreads();

        #pragma unroll
        for (int j = 0; j < 7; ++j) {
            int p = tid + j * 256;
            if (p < CO * V) {
                int co = p / V, v = p - co * V;
                for (int ci = 0; ci < CIH; ++ci) {
                    const float* wp = tconv_w + ((co * C) + cb + ci) * 9;
                    float w[9];
                    #pragma unroll
                    for (int d = 0; d < 9; ++d) w[d] = wp[d];
                    float fv[TBT + 8];
                    #pragma unroll
                    for (int sl = 0; sl < TBT + 8; ++sl) fv[sl] = s_f[ci][sl][v];
                    #pragma unroll
                    for (int tb = 0; tb < TBT; ++tb) {
                        float a = acc[j][tb];
                        #pragma unroll
                        for (int d = 0; d < 9; ++d) a += w[d] * fv[tb + d];
                        acc[j][tb] = a;
                    }
                }
            }
        }
        __syncthreads();
    }

    #pragma unroll
    for (int j = 0; j < 7; ++j) {
        int p = tid + j * 256;
        if (p < CO * V) {
            int co = p / V, v = p - co * V;
            float s3 = bn3_g[co] * rsqrtf(bn3_v[co] + BN_EPS);
            float b3 = bn3_b[co] - bn3_m[co] * s3;
            #pragma unroll
            for (int tb = 0; tb < TBT; ++tb) {
                int tt = t0 + tb;
                float y = acc[j][tb] * s3 + b3;
                y += x[((n * C + co) * T + tt) * V + v];
                out[((n * C + co) * T + tt) * V + v] = fmaxf(y, 0.f);
            }
        }
    }
}

extern "C" void kernel_launch(void* const* d_in, const int* in_sizes, int n_in,
                              void* d_out, int out_size, void* d_ws, size_t ws_size,
                              hipStream_t stream) {
    const float* x       = (const float*)d_in[0];
    const float* A       = (const float*)d_in[1];
    const float* bn1_g   = (const float*)d_in[2];
    const float* bn1_b   = (const float*)d_in[3];
    const float* bn1_m   = (const float*)d_in[4];
    const float* bn1_v   = (const float*)d_in[5];
    const float* pconv_w = (const float*)d_in[6];
    const float* pconv_b = (const float*)d_in[7];
    const float* wq      = (const float*)d_in[8];
    const float* wk      = (const float*)d_in[9];
    const float* wv      = (const float*)d_in[10];
    const float* fc_w    = (const float*)d_in[11];
    const float* ln_g    = (const float*)d_in[12];
    const float* ln_b    = (const float*)d_in[13];
    const float* gate_w  = (const float*)d_in[14];
    const float* bn2_g   = (const float*)d_in[15];
    const float* bn2_b   = (const float*)d_in[16];
    const float* bn2_m   = (const float*)d_in[17];
    const float* bn2_v   = (const float*)d_in[18];
    const float* tconv_w = (const float*)d_in[19];
    const float* tconv_b = (const float*)d_in[20];
    const float* bn3_g   = (const float*)d_in[21];
    const float* bn3_b   = (const float*)d_in[22];
    const float* bn3_m   = (const float*)d_in[23];
    const float* bn3_v   = (const float*)d_in[24];

    float* f_buf = (float*)d_ws;   // N*C*T*V floats = 104.9 MB
    float* outp  = (float*)d_out;

    scn_kernel<<<dim3(NB * T), dim3(256), 0, stream>>>(
        x, A, bn1_g, bn1_b, bn1_m, bn1_v, pconv_w, pconv_b, wq, wk, wv, fc_w,
        ln_g, ln_b, gate_w, bn2_g, bn2_b, bn2_m, bn2_v, f_buf);
    tcn_kernel<<<dim3(NB * (T / TBT)), dim3(256), 0, stream>>>(
        f_buf, x, tconv_w, tconv_b, bn3_g, bn3_b, bn3_m, bn3_v, outp);
}